// Round 9
// baseline (778.297 us; speedup 1.0000x reference)
//
#include <hip/hip_runtime.h>
#include <hip/hip_bf16.h>

#define N_FEATS_IN 128
#define BK_BITS 8
#define BK_SIZE 256      // nodes per bucket
#define EPB 4096         // edges per histogram/scatter block
#define MAXNB 512        // max buckets (N <= 131072)

typedef _Float16 h8 __attribute__((ext_vector_type(8)));
typedef float    f4v __attribute__((ext_vector_type(4)));
typedef float    f8v __attribute__((ext_vector_type(8)));

// ---------------------------------------------------------------------------
// scan / reduce helpers
// ---------------------------------------------------------------------------
__device__ inline int wave_incl_scan(int v) {
    const int lane = threadIdx.x & 63;
    for (int off = 1; off < 64; off <<= 1) {
        int u = __shfl_up(v, off, 64);
        if (lane >= off) v += u;
    }
    return v;
}

__device__ inline int block_excl_scan(int s, int* ws, int* total) {
    const int lane = threadIdx.x & 63, wid = threadIdx.x >> 6;
    int inc = wave_incl_scan(s);
    if (lane == 63) ws[wid] = inc;
    __syncthreads();
    int woff = 0;
#pragma unroll
    for (int w = 0; w < 4; ++w) woff += (w < wid) ? ws[w] : 0;
    if (total) *total = ws[0] + ws[1] + ws[2] + ws[3];
    return woff + inc - s;
}

// ---------------------------------------------------------------------------
// K1: per-block LDS bucket histograms of dst>>8 AND src>>8 (no global atomics)
// ---------------------------------------------------------------------------
__global__ __launch_bounds__(256) void hist_kernel(
    const int* __restrict__ src, const int* __restrict__ dst,
    int* __restrict__ bh_d, int* __restrict__ bh_s, int E, int NB) {
    __shared__ int hd[MAXNB];
    __shared__ int hs[MAXNB];
    const int t = threadIdx.x;
    for (int i = t; i < NB; i += 256) { hd[i] = 0; hs[i] = 0; }
    __syncthreads();
    const int base = blockIdx.x * EPB;
    const int end = min(base + EPB, E);
    for (int e = base + t; e < end; e += 256) {
        atomicAdd(&hd[dst[e] >> BK_BITS], 1);
        atomicAdd(&hs[src[e] >> BK_BITS], 1);
    }
    __syncthreads();
    for (int i = t; i < NB; i += 256) {
        bh_d[(size_t)blockIdx.x * NB + i] = hd[i];
        bh_s[(size_t)blockIdx.x * NB + i] = hs[i];
    }
}

// K2a: column sums of both matrices: tot_d[b], tot_s[b]
__global__ __launch_bounds__(256) void colsum2_kernel(
    const int* __restrict__ bh_d, const int* __restrict__ bh_s,
    int* __restrict__ tot_d, int* __restrict__ tot_s, int NBLK, int NB) {
    __shared__ int ws[8];
    const int b = blockIdx.x;
    const int t = threadIdx.x;
    const int lane = t & 63, wid = t >> 6;
    int sd = 0, ss = 0;
    for (int r = t; r < NBLK; r += 256) {
        sd += bh_d[(size_t)r * NB + b];
        ss += bh_s[(size_t)r * NB + b];
    }
    for (int off = 1; off < 64; off <<= 1) {
        sd += __shfl_down(sd, off, 64);
        ss += __shfl_down(ss, off, 64);
    }
    if (lane == 0) { ws[wid] = sd; ws[4 + wid] = ss; }
    __syncthreads();
    if (t == 0) tot_d[b] = ws[0] + ws[1] + ws[2] + ws[3];
    if (t == 1) tot_s[b] = ws[4] + ws[5] + ws[6] + ws[7];
}

// K2b: single block: gb_d = excl-scan(tot_d), gb_s = excl-scan(tot_s)
__global__ __launch_bounds__(256) void bscan2_kernel(
    const int* __restrict__ tot_d, const int* __restrict__ tot_s,
    int* __restrict__ gb_d, int* __restrict__ gb_s,
    int* __restrict__ row_ptr, int NB, int N, int E) {
    __shared__ int ws[4];
    const int t = threadIdx.x;
    {
        const int a = (2 * t < NB) ? tot_d[2 * t] : 0;
        const int b = (2 * t + 1 < NB) ? tot_d[2 * t + 1] : 0;
        const int excl = block_excl_scan(a + b, ws, nullptr);
        if (2 * t < NB) gb_d[2 * t] = excl;
        if (2 * t + 1 < NB) gb_d[2 * t + 1] = excl + a;
    }
    __syncthreads();
    {
        const int a = (2 * t < NB) ? tot_s[2 * t] : 0;
        const int b = (2 * t + 1 < NB) ? tot_s[2 * t + 1] : 0;
        const int excl = block_excl_scan(a + b, ws, nullptr);
        if (2 * t < NB) gb_s[2 * t] = excl;
        if (2 * t + 1 < NB) gb_s[2 * t + 1] = excl + a;
    }
    if (t == 0) { gb_d[NB] = E; gb_s[NB] = E; row_ptr[N] = E; }
}

// K2c: per column b: bh[blk][b] <- gb[b] + prefix over blk (both matrices)
__global__ __launch_bounds__(256) void colscan2_kernel(
    int* __restrict__ bh_d, int* __restrict__ bh_s,
    const int* __restrict__ gb_d, const int* __restrict__ gb_s,
    int NBLK, int NB) {
    __shared__ int ws[4];
    const int b = blockIdx.x;
    const int t = threadIdx.x;
    const int r0 = 2 * t, r1 = 2 * t + 1;
    {
        const int a = (r0 < NBLK) ? bh_d[(size_t)r0 * NB + b] : 0;
        const int c = (r1 < NBLK) ? bh_d[(size_t)r1 * NB + b] : 0;
        const int excl = block_excl_scan(a + c, ws, nullptr);
        const int base = gb_d[b];
        if (r0 < NBLK) bh_d[(size_t)r0 * NB + b] = base + excl;
        if (r1 < NBLK) bh_d[(size_t)r1 * NB + b] = base + excl + a;
    }
    __syncthreads();
    {
        const int a = (r0 < NBLK) ? bh_s[(size_t)r0 * NB + b] : 0;
        const int c = (r1 < NBLK) ? bh_s[(size_t)r1 * NB + b] : 0;
        const int excl = block_excl_scan(a + c, ws, nullptr);
        const int base = gb_s[b];
        if (r0 < NBLK) bh_s[(size_t)r0 * NB + b] = base + excl;
        if (r1 < NBLK) bh_s[(size_t)r1 * NB + b] = base + excl + a;
    }
}

// K3: dual scatter with LDS cursors:
//   ebuf[p_d] = src<<8 | (dst&255)   (dst-bucket-grouped, u32)
//   sbuf[p_s] = src&255              (src-bucket-grouped, u8)
__global__ __launch_bounds__(256) void scatter2_kernel(
    const int* __restrict__ src, const int* __restrict__ dst,
    const int* __restrict__ bh_d, const int* __restrict__ bh_s,
    unsigned int* __restrict__ ebuf, unsigned char* __restrict__ sbuf,
    int E, int NB) {
    __shared__ int cd[MAXNB];
    __shared__ int cs[MAXNB];
    const int t = threadIdx.x;
    for (int i = t; i < NB; i += 256) {
        cd[i] = bh_d[(size_t)blockIdx.x * NB + i];
        cs[i] = bh_s[(size_t)blockIdx.x * NB + i];
    }
    __syncthreads();
    const int base = blockIdx.x * EPB;
    const int end = min(base + EPB, E);
    for (int e = base + t; e < end; e += 256) {
        const int d = dst[e];
        const int s = src[e];
        const int pd = atomicAdd(&cd[d >> BK_BITS], 1);
        ebuf[pd] = ((unsigned)s << 8) | (unsigned)(d & (BK_SIZE - 1));
        const int ps = atomicAdd(&cs[s >> BK_BITS], 1);
        sbuf[ps] = (unsigned char)(s & (BK_SIZE - 1));
    }
}

// K4: per-bucket exact CSR: row_ptr, norm_dst (fused), edge_src
__global__ __launch_bounds__(256) void bucket_csr_kernel(
    const unsigned int* __restrict__ ebuf, const int* __restrict__ gb_d,
    int* __restrict__ row_ptr, float* __restrict__ norm_dst,
    int* __restrict__ edge_src, int N) {
    __shared__ int cnt[BK_SIZE];
    __shared__ int lro[BK_SIZE];
    __shared__ int ws[4];
    const int b = blockIdx.x;
    const int t = threadIdx.x;
    const int beg = gb_d[b], end = gb_d[b + 1];

    cnt[t] = 0;
    __syncthreads();
    for (int j = beg + t; j < end; j += 256)
        atomicAdd(&cnt[ebuf[j] & (BK_SIZE - 1)], 1);
    __syncthreads();

    const int v = cnt[t];
    const int excl = block_excl_scan(v, ws, nullptr);
    lro[t] = beg + excl;
    const int node = b * BK_SIZE + t;
    if (node < N) {
        row_ptr[node] = beg + excl;
        norm_dst[node] = rsqrtf(fmaxf((float)v, 1.0f));
    }
    __syncthreads();
    cnt[t] = 0;  // reuse as cursor
    __syncthreads();

    for (int j = beg + t; j < end; j += 256) {
        const unsigned int ed = ebuf[j];
        const int dl = ed & (BK_SIZE - 1);
        const int p = atomicAdd(&cnt[dl], 1);
        edge_src[lro[dl] + p] = (int)(ed >> 8);
    }
}

// K5: per-src-bucket count -> norm_src
__global__ __launch_bounds__(256) void count_src_kernel(
    const unsigned char* __restrict__ sbuf, const int* __restrict__ gb_s,
    float* __restrict__ norm_src, int N) {
    __shared__ int cnt[BK_SIZE];
    const int b = blockIdx.x;
    const int t = threadIdx.x;
    const int beg = gb_s[b], end = gb_s[b + 1];
    cnt[t] = 0;
    __syncthreads();
    for (int j = beg + t; j < end; j += 256)
        atomicAdd(&cnt[sbuf[j]], 1);
    __syncthreads();
    const int node = b * BK_SIZE + t;
    if (node < N)
        norm_src[node] = rsqrtf(fmaxf((float)cnt[t], 1.0f));
}

// ---------------------------------------------------------------------------
// MFMA GEMM: Y[n,OC] = (X[n,128] @ W[128,OC]) * scale[n], Y fp16.
// (unchanged — verified layouts)
// ---------------------------------------------------------------------------
template <int OC, bool XHALF>
__global__ __launch_bounds__(256) void mfma_gemm_kernel(
    const void* __restrict__ Xv, const float* __restrict__ W,
    const float* __restrict__ scale, _Float16* __restrict__ Y, int n) {
    constexpr int K = 128;
    constexpr int NT = OC / 16;
    constexpr int RPB = 128;
    __shared__ _Float16 Wf[NT * 4 * 64 * 8];

    const int tid = threadIdx.x;
    for (int i = tid; i < K * OC; i += 256) {
        const int k = i / OC, c = i % OC;
        const int t = c >> 4, s = k >> 5, q = (k >> 3) & 3, j = k & 7;
        Wf[(((t * 4 + s) * 4 + q) * 16 + (c & 15)) * 8 + j] = (_Float16)W[i];
    }
    __syncthreads();

    const int lane = tid & 63;
    const int wv = tid >> 6;
    const int m = lane & 15, q = lane >> 4;

#pragma unroll
    for (int it = 0; it < RPB / 64; ++it) {
        const int rbase = blockIdx.x * RPB + it * 64 + wv * 16;
        const int lrow = min(rbase + m, n - 1);

        h8 a[4];
        if constexpr (XHALF) {
            const _Float16* X = (const _Float16*)Xv;
            const _Float16* p = &X[(size_t)lrow * K + q * 8];
#pragma unroll
            for (int s = 0; s < 4; ++s) a[s] = *(const h8*)(p + s * 32);
        } else {
            const float* X = (const float*)Xv;
            const float* p = &X[(size_t)lrow * K + q * 8];
#pragma unroll
            for (int s = 0; s < 4; ++s) {
                const float4 u0 = *(const float4*)(p + s * 32);
                const float4 u1 = *(const float4*)(p + s * 32 + 4);
                h8 v;
                v[0] = (_Float16)u0.x; v[1] = (_Float16)u0.y;
                v[2] = (_Float16)u0.z; v[3] = (_Float16)u0.w;
                v[4] = (_Float16)u1.x; v[5] = (_Float16)u1.y;
                v[6] = (_Float16)u1.z; v[7] = (_Float16)u1.w;
                a[s] = v;
            }
        }

        f4v acc[NT];
#pragma unroll
        for (int t = 0; t < NT; ++t) acc[t] = (f4v)0.0f;

#pragma unroll
        for (int s = 0; s < 4; ++s) {
#pragma unroll
            for (int t = 0; t < NT; ++t) {
                const h8 b = *(const h8*)&Wf[((t * 4 + s) * 64 + lane) * 8];
                acc[t] = __builtin_amdgcn_mfma_f32_16x16x32_f16(
                    a[s], b, acc[t], 0, 0, 0);
            }
        }

#pragma unroll
        for (int r = 0; r < 4; ++r) {
            const int orow = rbase + q * 4 + r;
            if (orow < n) {
                const float sc = scale[orow];
#pragma unroll
                for (int t = 0; t < NT; ++t)
                    Y[(size_t)orow * OC + t * 16 + m] =
                        (_Float16)(acc[t][r] * sc);
            }
        }
    }
}

// ---------------------------------------------------------------------------
// XCD-sharded pull aggregation: feature dim split into 8 chunks; chunk =
// blockIdx.x & 7 so all blocks of chunk c land on XCD c (round-robin
// dispatch heuristic). Per-XCD L2 then only holds its 1/8 feature slice
// (3.2 MB / 1.6 MB — L2-resident). Edge indices are streamed with
// nontemporal loads and outputs with nontemporal stores so they don't
// evict the slice. Correct regardless of actual XCD mapping.
// ---------------------------------------------------------------------------
template <int FEAT, bool RELU, bool OUT_HALF>
__global__ __launch_bounds__(256) void gather_chunk_kernel(
    const _Float16* __restrict__ T, const int* __restrict__ row_ptr,
    const int* __restrict__ edge_src, const float* __restrict__ norm_dst,
    const float* __restrict__ bias, void* __restrict__ outv, int n) {
    constexpr int CF = FEAT / 8;     // feats per chunk (16 / 8)
    constexpr int TPN = CF / 8;      // lanes per node (2 / 1)
    constexpr int NPB = 256 / TPN;   // nodes per block (128 / 256)
    constexpr int VS = FEAT / 8;     // h8 vectors per row

    const int chunk = blockIdx.x & 7;
    const int grp = blockIdx.x >> 3;
    const int node = grp * NPB + threadIdx.x / TPN;
    const int f8 = threadIdx.x % TPN;
    if (node >= n) return;
    const int beg = __builtin_nontemporal_load(&row_ptr[node]);
    const int end = __builtin_nontemporal_load(&row_ptr[node + 1]);
    const h8* T8 = (const h8*)T;
    const int voff = chunk * TPN + f8;

    f8v acc = (f8v)0.0f;
    int j = beg;
    for (; j + 3 < end; j += 4) {
        int s[4];
#pragma unroll
        for (int u = 0; u < 4; ++u)
            s[u] = __builtin_nontemporal_load(&edge_src[j + u]);
        h8 a[4];
#pragma unroll
        for (int u = 0; u < 4; ++u) a[u] = T8[(size_t)s[u] * VS + voff];
#pragma unroll
        for (int u = 0; u < 4; ++u)
            acc += __builtin_convertvector(a[u], f8v);
    }
    for (; j < end; ++j) {
        const int s = __builtin_nontemporal_load(&edge_src[j]);
        acc += __builtin_convertvector(T8[(size_t)s * VS + voff], f8v);
    }

    const float nd = norm_dst[node];
    float r[8];
#pragma unroll
    for (int k = 0; k < 8; ++k) {
        r[k] = acc[k] * nd + bias[chunk * CF + f8 * 8 + k];
        if constexpr (RELU) r[k] = fmaxf(r[k], 0.0f);
    }

    if constexpr (OUT_HALF) {
        _Float16* out = (_Float16*)outv;
        h8 o;
#pragma unroll
        for (int k = 0; k < 8; ++k) o[k] = (_Float16)r[k];
        __builtin_nontemporal_store(
            o, (h8*)&out[(size_t)node * FEAT + chunk * CF + f8 * 8]);
    } else {
        float* out = (float*)outv;
        f4v o0 = {r[0], r[1], r[2], r[3]};
        f4v o1 = {r[4], r[5], r[6], r[7]};
        float* p = &out[(size_t)node * FEAT + chunk * CF + f8 * 8];
        __builtin_nontemporal_store(o0, (f4v*)p);
        __builtin_nontemporal_store(o1, (f4v*)(p + 4));
    }
}

extern "C" void kernel_launch(void* const* d_in, const int* in_sizes, int n_in,
                              void* d_out, int out_size, void* d_ws, size_t ws_size,
                              hipStream_t stream) {
    const float* x   = (const float*)d_in[0];   // [N,128]
    const int*   src = (const int*)d_in[1];     // [E]
    const int*   dst = (const int*)d_in[2];     // [E]
    const float* W1  = (const float*)d_in[3];   // [128,128]
    const float* b1  = (const float*)d_in[4];   // [128]
    const float* W2  = (const float*)d_in[5];   // [128,64]
    const float* b2  = (const float*)d_in[6];   // [64]
    float* out = (float*)d_out;

    const int N = in_sizes[0] / N_FEATS_IN;     // 100000
    const int E = in_sizes[1];                  // 1600000
    const int NB = (N + BK_SIZE - 1) / BK_SIZE; // 391 buckets
    const int NBLK = (E + EPB - 1) / EPB;       // 391 edge blocks

    auto align4 = [](size_t w) { return (w + 3) & ~(size_t)3; };
    char* base = (char*)d_ws;
    size_t off = 0;
    auto take = [&](size_t words) {
        char* p = base + off * 4;
        off = align4(off + words);
        return p;
    };
    int*   tot_d    = (int*)take(NB);
    int*   tot_s    = (int*)take(NB);
    int*   gb_d     = (int*)take(NB + 1);
    int*   gb_s     = (int*)take(NB + 1);
    int*   bh_d     = (int*)take((size_t)NBLK * NB);
    int*   bh_s     = (int*)take((size_t)NBLK * NB);
    unsigned int*  ebuf = (unsigned int*)take(E);
    unsigned char* sbuf = (unsigned char*)take((E + 3) / 4);
    int*   row_ptr  = (int*)take(N + 1);
    int*   edge_src = (int*)take(E);
    float* norms    = (float*)take(2 * (size_t)N);
    _Float16* t1    = (_Float16*)take((size_t)N * 64);  // N x 128 fp16
    _Float16* h1    = (_Float16*)take((size_t)N * 64);  // N x 128 fp16
    _Float16* t2    = (_Float16*)take((size_t)N * 32);  // N x 64  fp16
    float* norm_src = norms;
    float* norm_dst = norms + N;

    // ---- CSR build (dual counting sort; zero global atomics) ----
    hist_kernel<<<NBLK, 256, 0, stream>>>(src, dst, bh_d, bh_s, E, NB);
    colsum2_kernel<<<NB, 256, 0, stream>>>(bh_d, bh_s, tot_d, tot_s, NBLK, NB);
    bscan2_kernel<<<1, 256, 0, stream>>>(tot_d, tot_s, gb_d, gb_s, row_ptr,
                                         NB, N, E);
    colscan2_kernel<<<NB, 256, 0, stream>>>(bh_d, bh_s, gb_d, gb_s, NBLK, NB);
    scatter2_kernel<<<NBLK, 256, 0, stream>>>(src, dst, bh_d, bh_s, ebuf, sbuf,
                                              E, NB);
    bucket_csr_kernel<<<NB, 256, 0, stream>>>(ebuf, gb_d, row_ptr, norm_dst,
                                              edge_src, N);
    count_src_kernel<<<NB, 256, 0, stream>>>(sbuf, gb_s, norm_src, N);

    // ---- layer 1 ----
    mfma_gemm_kernel<128, false><<<(N + 127) / 128, 256, 0, stream>>>(
        x, W1, norm_src, t1, N);
    gather_chunk_kernel<128, true, true>
        <<<8 * ((N + 127) / 128), 256, 0, stream>>>(
        t1, row_ptr, edge_src, norm_dst, b1, h1, N);

    // ---- layer 2 ----
    mfma_gemm_kernel<64, true><<<(N + 127) / 128, 256, 0, stream>>>(
        h1, W2, norm_src, t2, N);
    gather_chunk_kernel<64, false, false>
        <<<8 * ((N + 255) / 256), 256, 0, stream>>>(
        t2, row_ptr, edge_src, norm_dst, b2, out, N);
}

// Round 10
// 336.401 us; speedup vs baseline: 2.3136x; 2.3136x over previous
//
#include <hip/hip_runtime.h>
#include <hip/hip_bf16.h>

#define N_FEATS_IN 128
#define BK_BITS 8
#define BK_SIZE 256      // nodes per bucket
#define EPB 4096         // edges per histogram/scatter block
#define MAXNB 512        // max buckets (N <= 131072)

typedef _Float16 h8 __attribute__((ext_vector_type(8)));
typedef float    f4v __attribute__((ext_vector_type(4)));
typedef float    f8v __attribute__((ext_vector_type(8)));

// ---------------------------------------------------------------------------
// scan / reduce helpers
// ---------------------------------------------------------------------------
__device__ inline int wave_incl_scan(int v) {
    const int lane = threadIdx.x & 63;
    for (int off = 1; off < 64; off <<= 1) {
        int u = __shfl_up(v, off, 64);
        if (lane >= off) v += u;
    }
    return v;
}

// 256-thread block exclusive scan; ws = LDS int[4]; syncs internally after
// the ws write. Caller must __syncthreads() before the next call (ws reuse).
__device__ inline int block_excl_scan(int s, int* ws, int* total) {
    const int lane = threadIdx.x & 63, wid = threadIdx.x >> 6;
    int inc = wave_incl_scan(s);
    if (lane == 63) ws[wid] = inc;
    __syncthreads();
    int woff = 0;
#pragma unroll
    for (int w = 0; w < 4; ++w) woff += (w < wid) ? ws[w] : 0;
    if (total) *total = ws[0] + ws[1] + ws[2] + ws[3];
    return woff + inc - s;
}

// ---------------------------------------------------------------------------
// K1: per-block LDS bucket histograms of dst>>8 AND src>>8 (no global atomics)
// ---------------------------------------------------------------------------
__global__ __launch_bounds__(256) void hist_kernel(
    const int* __restrict__ src, const int* __restrict__ dst,
    int* __restrict__ bh_d, int* __restrict__ bh_s, int E, int NB) {
    __shared__ int hd[MAXNB];
    __shared__ int hs[MAXNB];
    const int t = threadIdx.x;
    for (int i = t; i < NB; i += 256) { hd[i] = 0; hs[i] = 0; }
    __syncthreads();
    const int base = blockIdx.x * EPB;
    const int end = min(base + EPB, E);
    for (int e = base + t; e < end; e += 256) {
        atomicAdd(&hd[dst[e] >> BK_BITS], 1);
        atomicAdd(&hs[src[e] >> BK_BITS], 1);
    }
    __syncthreads();
    for (int i = t; i < NB; i += 256) {
        bh_d[(size_t)blockIdx.x * NB + i] = hd[i];
        bh_s[(size_t)blockIdx.x * NB + i] = hs[i];
    }
}

// K2a: per column b: in-place exclusive prefix over blk of bh[blk][b]
//      (LOCAL, without bucket base) + column total -> tot[b]. Both matrices.
//      Replaces the old colsum+colscan pair; scatter adds gb[b] itself.
__global__ __launch_bounds__(256) void colprefix2_kernel(
    int* __restrict__ bh_d, int* __restrict__ bh_s,
    int* __restrict__ tot_d, int* __restrict__ tot_s, int NBLK, int NB) {
    __shared__ int ws[4];
    const int b = blockIdx.x;
    const int t = threadIdx.x;
    int carry = 0;
    for (int base = 0; base < NBLK; base += 256) {
        const int r = base + t;
        const int v = (r < NBLK) ? bh_d[(size_t)r * NB + b] : 0;
        int total;
        const int e = block_excl_scan(v, ws, &total);
        if (r < NBLK) bh_d[(size_t)r * NB + b] = carry + e;
        carry += total;
        __syncthreads();
    }
    if (t == 0) tot_d[b] = carry;
    carry = 0;
    for (int base = 0; base < NBLK; base += 256) {
        const int r = base + t;
        const int v = (r < NBLK) ? bh_s[(size_t)r * NB + b] : 0;
        int total;
        const int e = block_excl_scan(v, ws, &total);
        if (r < NBLK) bh_s[(size_t)r * NB + b] = carry + e;
        carry += total;
        __syncthreads();
    }
    if (t == 0) tot_s[b] = carry;
}

// K2b: single block: gb_d = excl-scan(tot_d), gb_s = excl-scan(tot_s)
__global__ __launch_bounds__(256) void bscan2_kernel(
    const int* __restrict__ tot_d, const int* __restrict__ tot_s,
    int* __restrict__ gb_d, int* __restrict__ gb_s,
    int* __restrict__ row_ptr, int NB, int N, int E) {
    __shared__ int ws[4];
    const int t = threadIdx.x;
    {
        const int a = (2 * t < NB) ? tot_d[2 * t] : 0;
        const int b = (2 * t + 1 < NB) ? tot_d[2 * t + 1] : 0;
        const int excl = block_excl_scan(a + b, ws, nullptr);
        if (2 * t < NB) gb_d[2 * t] = excl;
        if (2 * t + 1 < NB) gb_d[2 * t + 1] = excl + a;
    }
    __syncthreads();
    {
        const int a = (2 * t < NB) ? tot_s[2 * t] : 0;
        const int b = (2 * t + 1 < NB) ? tot_s[2 * t + 1] : 0;
        const int excl = block_excl_scan(a + b, ws, nullptr);
        if (2 * t < NB) gb_s[2 * t] = excl;
        if (2 * t + 1 < NB) gb_s[2 * t + 1] = excl + a;
    }
    if (t == 0) { gb_d[NB] = E; gb_s[NB] = E; row_ptr[N] = E; }
}

// K3: dual scatter with LDS cursors (cursor = local prefix + bucket base):
//   ebuf[p_d] = src<<8 | (dst&255)   (dst-bucket-grouped, u32)
//   sbuf[p_s] = src&255              (src-bucket-grouped, u8)
__global__ __launch_bounds__(256) void scatter2_kernel(
    const int* __restrict__ src, const int* __restrict__ dst,
    const int* __restrict__ bh_d, const int* __restrict__ bh_s,
    const int* __restrict__ gb_d, const int* __restrict__ gb_s,
    unsigned int* __restrict__ ebuf, unsigned char* __restrict__ sbuf,
    int E, int NB) {
    __shared__ int cd[MAXNB];
    __shared__ int cs[MAXNB];
    const int t = threadIdx.x;
    for (int i = t; i < NB; i += 256) {
        cd[i] = bh_d[(size_t)blockIdx.x * NB + i] + gb_d[i];
        cs[i] = bh_s[(size_t)blockIdx.x * NB + i] + gb_s[i];
    }
    __syncthreads();
    const int base = blockIdx.x * EPB;
    const int end = min(base + EPB, E);
    for (int e = base + t; e < end; e += 256) {
        const int d = dst[e];
        const int s = src[e];
        const int pd = atomicAdd(&cd[d >> BK_BITS], 1);
        ebuf[pd] = ((unsigned)s << 8) | (unsigned)(d & (BK_SIZE - 1));
        const int ps = atomicAdd(&cs[s >> BK_BITS], 1);
        sbuf[ps] = (unsigned char)(s & (BK_SIZE - 1));
    }
}

// K4: per-bucket exact CSR (row_ptr, norm_dst, edge_src) + fused src-side
//     count -> norm_src (independent work, same grid).
__global__ __launch_bounds__(256) void bucket_csr_kernel(
    const unsigned int* __restrict__ ebuf, const int* __restrict__ gb_d,
    const unsigned char* __restrict__ sbuf, const int* __restrict__ gb_s,
    int* __restrict__ row_ptr, float* __restrict__ norm_dst,
    float* __restrict__ norm_src, int* __restrict__ edge_src, int N) {
    __shared__ int cnt[BK_SIZE];
    __shared__ int lro[BK_SIZE];
    __shared__ int ws[4];
    const int b = blockIdx.x;
    const int t = threadIdx.x;
    const int beg = gb_d[b], end = gb_d[b + 1];
    const int node = b * BK_SIZE + t;

    cnt[t] = 0;
    __syncthreads();
    for (int j = beg + t; j < end; j += 256)
        atomicAdd(&cnt[ebuf[j] & (BK_SIZE - 1)], 1);
    __syncthreads();

    const int v = cnt[t];
    const int excl = block_excl_scan(v, ws, nullptr);
    lro[t] = beg + excl;
    if (node < N) {
        row_ptr[node] = beg + excl;
        norm_dst[node] = rsqrtf(fmaxf((float)v, 1.0f));
    }
    __syncthreads();
    cnt[t] = 0;  // reuse as cursor
    __syncthreads();

    for (int j = beg + t; j < end; j += 256) {
        const unsigned int ed = ebuf[j];
        const int dl = ed & (BK_SIZE - 1);
        const int p = atomicAdd(&cnt[dl], 1);
        edge_src[lro[dl] + p] = (int)(ed >> 8);
    }

    // ---- fused src-side degree count -> norm_src ----
    __syncthreads();
    cnt[t] = 0;
    __syncthreads();
    const int sb = gb_s[b], se = gb_s[b + 1];
    for (int j = sb + t; j < se; j += 256)
        atomicAdd(&cnt[sbuf[j]], 1);
    __syncthreads();
    if (node < N)
        norm_src[node] = rsqrtf(fmaxf((float)cnt[t], 1.0f));
}

// ---------------------------------------------------------------------------
// MFMA GEMM: Y[n,OC] = (X[n,128] @ W[128,OC]) * scale[n], Y fp16.
// (unchanged — verified layouts)
// ---------------------------------------------------------------------------
template <int OC, bool XHALF>
__global__ __launch_bounds__(256) void mfma_gemm_kernel(
    const void* __restrict__ Xv, const float* __restrict__ W,
    const float* __restrict__ scale, _Float16* __restrict__ Y, int n) {
    constexpr int K = 128;
    constexpr int NT = OC / 16;
    constexpr int RPB = 128;
    __shared__ _Float16 Wf[NT * 4 * 64 * 8];

    const int tid = threadIdx.x;
    for (int i = tid; i < K * OC; i += 256) {
        const int k = i / OC, c = i % OC;
        const int t = c >> 4, s = k >> 5, q = (k >> 3) & 3, j = k & 7;
        Wf[(((t * 4 + s) * 4 + q) * 16 + (c & 15)) * 8 + j] = (_Float16)W[i];
    }
    __syncthreads();

    const int lane = tid & 63;
    const int wv = tid >> 6;
    const int m = lane & 15, q = lane >> 4;

#pragma unroll
    for (int it = 0; it < RPB / 64; ++it) {
        const int rbase = blockIdx.x * RPB + it * 64 + wv * 16;
        const int lrow = min(rbase + m, n - 1);

        h8 a[4];
        if constexpr (XHALF) {
            const _Float16* X = (const _Float16*)Xv;
            const _Float16* p = &X[(size_t)lrow * K + q * 8];
#pragma unroll
            for (int s = 0; s < 4; ++s) a[s] = *(const h8*)(p + s * 32);
        } else {
            const float* X = (const float*)Xv;
            const float* p = &X[(size_t)lrow * K + q * 8];
#pragma unroll
            for (int s = 0; s < 4; ++s) {
                const float4 u0 = *(const float4*)(p + s * 32);
                const float4 u1 = *(const float4*)(p + s * 32 + 4);
                h8 v;
                v[0] = (_Float16)u0.x; v[1] = (_Float16)u0.y;
                v[2] = (_Float16)u0.z; v[3] = (_Float16)u0.w;
                v[4] = (_Float16)u1.x; v[5] = (_Float16)u1.y;
                v[6] = (_Float16)u1.z; v[7] = (_Float16)u1.w;
                a[s] = v;
            }
        }

        f4v acc[NT];
#pragma unroll
        for (int t = 0; t < NT; ++t) acc[t] = (f4v)0.0f;

#pragma unroll
        for (int s = 0; s < 4; ++s) {
#pragma unroll
            for (int t = 0; t < NT; ++t) {
                const h8 b = *(const h8*)&Wf[((t * 4 + s) * 64 + lane) * 8];
                acc[t] = __builtin_amdgcn_mfma_f32_16x16x32_f16(
                    a[s], b, acc[t], 0, 0, 0);
            }
        }

#pragma unroll
        for (int r = 0; r < 4; ++r) {
            const int orow = rbase + q * 4 + r;
            if (orow < n) {
                const float sc = scale[orow];
#pragma unroll
                for (int t = 0; t < NT; ++t)
                    Y[(size_t)orow * OC + t * 16 + m] =
                        (_Float16)(acc[t][r] * sc);
            }
        }
    }
}

// ---------------------------------------------------------------------------
// pull aggregation + fused epilogue over fp16 rows (R7 version — proven)
// ---------------------------------------------------------------------------
template <int FEAT, bool RELU, bool OUT_HALF>
__global__ __launch_bounds__(256) void gather_agg_kernel(
    const _Float16* __restrict__ T, const int* __restrict__ row_ptr,
    const int* __restrict__ edge_src, const float* __restrict__ norm_dst,
    const float* __restrict__ bias, void* __restrict__ outv, int n) {
    constexpr int TPN = FEAT / 8;
    constexpr int NPB = 256 / TPN;
    const int node = blockIdx.x * NPB + threadIdx.x / TPN;
    const int f8 = threadIdx.x % TPN;
    if (node >= n) return;
    const int beg = row_ptr[node];
    const int end = row_ptr[node + 1];
    const h8* T8 = (const h8*)T;

    f8v acc = (f8v)0.0f;
    int j = beg;
    for (; j + 7 < end; j += 8) {
        int s[8];
#pragma unroll
        for (int u = 0; u < 8; ++u) s[u] = edge_src[j + u];
        h8 a[8];
#pragma unroll
        for (int u = 0; u < 8; ++u) a[u] = T8[(size_t)s[u] * TPN + f8];
#pragma unroll
        for (int u = 0; u < 8; ++u)
            acc += __builtin_convertvector(a[u], f8v);
    }
    for (; j + 3 < end; j += 4) {
        int s[4];
#pragma unroll
        for (int u = 0; u < 4; ++u) s[u] = edge_src[j + u];
        h8 a[4];
#pragma unroll
        for (int u = 0; u < 4; ++u) a[u] = T8[(size_t)s[u] * TPN + f8];
#pragma unroll
        for (int u = 0; u < 4; ++u)
            acc += __builtin_convertvector(a[u], f8v);
    }
    for (; j < end; ++j)
        acc += __builtin_convertvector(T8[(size_t)edge_src[j] * TPN + f8], f8v);

    const float nd = norm_dst[node];
    float r[8];
#pragma unroll
    for (int k = 0; k < 8; ++k) {
        r[k] = acc[k] * nd + bias[f8 * 8 + k];
        if constexpr (RELU) r[k] = fmaxf(r[k], 0.0f);
    }

    if constexpr (OUT_HALF) {
        _Float16* out = (_Float16*)outv;
        h8 o;
#pragma unroll
        for (int k = 0; k < 8; ++k) o[k] = (_Float16)r[k];
        *(h8*)&out[(size_t)node * FEAT + f8 * 8] = o;
    } else {
        float* out = (float*)outv;
        float4 o0 = make_float4(r[0], r[1], r[2], r[3]);
        float4 o1 = make_float4(r[4], r[5], r[6], r[7]);
        *(float4*)&out[(size_t)node * FEAT + f8 * 8] = o0;
        *(float4*)&out[(size_t)node * FEAT + f8 * 8 + 4] = o1;
    }
}

extern "C" void kernel_launch(void* const* d_in, const int* in_sizes, int n_in,
                              void* d_out, int out_size, void* d_ws, size_t ws_size,
                              hipStream_t stream) {
    const float* x   = (const float*)d_in[0];   // [N,128]
    const int*   src = (const int*)d_in[1];     // [E]
    const int*   dst = (const int*)d_in[2];     // [E]
    const float* W1  = (const float*)d_in[3];   // [128,128]
    const float* b1  = (const float*)d_in[4];   // [128]
    const float* W2  = (const float*)d_in[5];   // [128,64]
    const float* b2  = (const float*)d_in[6];   // [64]
    float* out = (float*)d_out;

    const int N = in_sizes[0] / N_FEATS_IN;     // 100000
    const int E = in_sizes[1];                  // 1600000
    const int NB = (N + BK_SIZE - 1) / BK_SIZE; // 391 buckets
    const int NBLK = (E + EPB - 1) / EPB;       // 391 edge blocks

    auto align4 = [](size_t w) { return (w + 3) & ~(size_t)3; };
    char* base = (char*)d_ws;
    size_t off = 0;
    auto take = [&](size_t words) {
        char* p = base + off * 4;
        off = align4(off + words);
        return p;
    };
    int*   tot_d    = (int*)take(NB);
    int*   tot_s    = (int*)take(NB);
    int*   gb_d     = (int*)take(NB + 1);
    int*   gb_s     = (int*)take(NB + 1);
    int*   bh_d     = (int*)take((size_t)NBLK * NB);
    int*   bh_s     = (int*)take((size_t)NBLK * NB);
    unsigned int*  ebuf = (unsigned int*)take(E);
    unsigned char* sbuf = (unsigned char*)take((E + 3) / 4);
    int*   row_ptr  = (int*)take(N + 1);
    int*   edge_src = (int*)take(E);
    float* norms    = (float*)take(2 * (size_t)N);
    _Float16* t1    = (_Float16*)take((size_t)N * 64);  // N x 128 fp16
    _Float16* h1    = (_Float16*)take((size_t)N * 64);  // N x 128 fp16
    _Float16* t2    = (_Float16*)take((size_t)N * 32);  // N x 64  fp16
    float* norm_src = norms;
    float* norm_dst = norms + N;

    // ---- CSR build (dual counting sort; zero global atomics; 5 kernels) ----
    hist_kernel<<<NBLK, 256, 0, stream>>>(src, dst, bh_d, bh_s, E, NB);
    colprefix2_kernel<<<NB, 256, 0, stream>>>(bh_d, bh_s, tot_d, tot_s,
                                              NBLK, NB);
    bscan2_kernel<<<1, 256, 0, stream>>>(tot_d, tot_s, gb_d, gb_s, row_ptr,
                                         NB, N, E);
    scatter2_kernel<<<NBLK, 256, 0, stream>>>(src, dst, bh_d, bh_s, gb_d, gb_s,
                                              ebuf, sbuf, E, NB);
    bucket_csr_kernel<<<NB, 256, 0, stream>>>(ebuf, gb_d, sbuf, gb_s, row_ptr,
                                              norm_dst, norm_src, edge_src, N);

    // ---- layer 1 ----
    mfma_gemm_kernel<128, false><<<(N + 127) / 128, 256, 0, stream>>>(
        x, W1, norm_src, t1, N);
    gather_agg_kernel<128, true, true><<<(N + 15) / 16, 256, 0, stream>>>(
        t1, row_ptr, edge_src, norm_dst, b1, h1, N);

    // ---- layer 2 ----
    mfma_gemm_kernel<64, true><<<(N + 127) / 128, 256, 0, stream>>>(
        h1, W2, norm_src, t2, N);
    gather_agg_kernel<64, false, false><<<(N + 31) / 32, 256, 0, stream>>>(
        t2, row_ptr, edge_src, norm_dst, b2, out, N);
}